// Round 25
// baseline (110.637 us; speedup 1.0000x reference)
//
#include <hip/hip_runtime.h>

#define IN_DIM 128
#define OUT_DIM 128
#define PADCAP 1792   // per-bucket capacity: max count ~1184 + 64*7 pad = 1632 < 1792
#define EPB 8192      // edges per place block (196 blocks)

typedef short bf16x8 __attribute__((ext_vector_type(8)));
typedef float f32x4 __attribute__((ext_vector_type(4)));
typedef float f32x2 __attribute__((ext_vector_type(2)));
typedef unsigned int u32x4 __attribute__((ext_vector_type(4)));

__device__ __forceinline__ unsigned short f2bf(float f) {
    union { float f; unsigned int u; } v; v.f = f;
    unsigned int u = v.u;
    u += 0x7FFFu + ((u >> 16) & 1u);   // round-to-nearest-even
    return (unsigned short)(u >> 16);
}

// ---------------------------------------------------------------------------
// prep: fused convertq (x -> fp8, ONE full-row plane [(nN+1)][128]) +
// convertW (MFMA fragment layout) + cursor init + sentinel row.
// ---------------------------------------------------------------------------
__global__ __launch_bounds__(256) void prep_kernel(const float* __restrict__ x,
                                                   unsigned char* __restrict__ xq,
                                                   const float* __restrict__ W,
                                                   unsigned short* __restrict__ WF,
                                                   int* __restrict__ cursor,
                                                   int nN, int total8, int nconv, int nb) {
    const int b = blockIdx.x;
    const int t = threadIdx.x;
    if (b < nconv) {
        int i = b * 256 + t;
        if (i >= total8) return;
        const float4* p = (const float4*)x + (size_t)i * 2;
        float4 v0 = p[0], v1 = p[1];
        int w0 = 0, w1 = 0;
        w0 = __builtin_amdgcn_cvt_pk_fp8_f32(v0.x, v0.y, w0, false);
        w0 = __builtin_amdgcn_cvt_pk_fp8_f32(v0.z, v0.w, w0, true);
        w1 = __builtin_amdgcn_cvt_pk_fp8_f32(v1.x, v1.y, w1, false);
        w1 = __builtin_amdgcn_cvt_pk_fp8_f32(v1.z, v1.w, w1, true);
        uint2 o; o.x = (unsigned int)w0; o.y = (unsigned int)w1;
        *(uint2*)(xq + (size_t)i * 8) = o;   // row-major [(nN+1)][128]
    } else if (b < nconv + 16) {
        int tt = (b - nconv) * 256 + t;   // 0..4095
        int frag = tt >> 6, lane = tt & 63;
        int f = frag >> 3, c = frag & 7;
        int col = c * 16 + (lane & 15);
        int kbase = f * 32 + (lane >> 4) * 8;
        bf16x8 h;
#pragma unroll
        for (int i = 0; i < 8; i++)
            h[i] = (short)f2bf(W[(size_t)(kbase + i) * OUT_DIM + col]);
        *(bf16x8*)(WF + (size_t)tt * 8) = h;
    } else if (b == nconv + 16) {
        if (t < 32)
            *(unsigned int*)(xq + (size_t)nN * 128 + t * 4) = 0u;   // sentinel row
    } else {
        int i = (b - nconv - 17) * 256 + t;
        if (i < nb) cursor[i] = i * PADCAP;
    }
}

// ---------------------------------------------------------------------------
// place: edges -> per-bucket segments. payload = (dstlocal<<17)|src.
// ---------------------------------------------------------------------------
__global__ __launch_bounds__(1024) void place_kernel(const int* __restrict__ src,
                                                     const int* __restrict__ dst,
                                                     int* __restrict__ cursor,
                                                     unsigned int* __restrict__ csr_packed,
                                                     int nE, int nb) {
    __shared__ int lcnt[2048];
    __shared__ int lbase[2048];
    const int t = threadIdx.x;
    for (int i = t; i < nb; i += 1024) lcnt[i] = 0;
    __syncthreads();
    const int e0 = blockIdx.x * EPB;
    unsigned int meta[EPB / 1024];
#pragma unroll
    for (int k = 0; k < EPB / 1024; k++) {
        int e = e0 + k * 1024 + t;
        if (e < nE) {
            int d = dst[e];
            int bk = d >> 6, dl = d & 63;
            int r = atomicAdd(&lcnt[bk], 1);
            meta[k] = ((unsigned)bk << 20) | ((unsigned)dl << 14) | (unsigned)r;
        } else meta[k] = 0xFFFFFFFFu;
    }
    __syncthreads();
    for (int i = t; i < nb; i += 1024) {
        int c = lcnt[i];
        lbase[i] = c ? atomicAdd(&cursor[i], c) : 0;   // absolute base
    }
    __syncthreads();
#pragma unroll
    for (int k = 0; k < EPB / 1024; k++) {
        if (meta[k] != 0xFFFFFFFFu) {
            int e = e0 + k * 1024 + t;
            unsigned int m = meta[k];
            int bk = m >> 20, dl = (m >> 14) & 63, r = m & 0x3FFF;
            csr_packed[lbase[bk] + r] = ((unsigned)dl << 17) | (unsigned)src[e];
        }
    }
}

// ---------------------------------------------------------------------------
// fused: ONE block per bucket. sort -> full-row fp8 gather -> Ntile (LDS) ->
// barrier -> zero-barrier MFMA GEMM. CHANGES vs r24: (a) launch_bounds
// (256,6) — LDS 26.1KB allows 6 blocks/CU, was capped at 4; (b) x-half
// prefetched into registers BEFORE the gather (asm-anchored so the scheduler
// can't sink it) — GEMM phase no longer stalls on global x loads.
// ---------------------------------------------------------------------------
__global__ __launch_bounds__(256, 6) void fused_kernel(const unsigned char* __restrict__ xq,
                                                       const unsigned int* __restrict__ csr_packed,
                                                       const int* __restrict__ cursor,
                                                       const unsigned short* __restrict__ WF,
                                                       const float* __restrict__ x,
                                                       const float* __restrict__ bias,
                                                       float* __restrict__ out, int nN) {
    __shared__ unsigned int el[PADCAP];
    __shared__ __align__(16) short Ntile[64 * 136];
    __shared__ int bcnt[64];
    __shared__ int bpst[64];
    __shared__ int bst[64];
    __shared__ int bdg[64];
    __shared__ int brw[64];

    const int bucket = blockIdx.x;
    const int t = threadIdx.x;
    const int lane = t & 63;
    const int wave = t >> 6;

    const size_t e0 = (size_t)bucket * PADCAP;
    int n = cursor[bucket] - bucket * PADCAP;
    if (n > PADCAP) n = PADCAP;

    // ---- prefetch x-half fragments for the GEMM (consumed after the barrier)
    const int arow = wave * 16 + (lane & 15);
    const int koff = (lane >> 4) * 8;
    const int rowc = min(bucket * 64 + arow, nN - 1);
    const float* xrow = x + (size_t)rowc * IN_DIM;
    f32x4 xp0 = *(const f32x4*)(xrow + 0 * 32 + koff);
    f32x4 xp1 = *(const f32x4*)(xrow + 0 * 32 + koff + 4);
    f32x4 xp2 = *(const f32x4*)(xrow + 1 * 32 + koff);
    f32x4 xp3 = *(const f32x4*)(xrow + 1 * 32 + koff + 4);
    f32x4 xp4 = *(const f32x4*)(xrow + 2 * 32 + koff);
    f32x4 xp5 = *(const f32x4*)(xrow + 2 * 32 + koff + 4);
    f32x4 xp6 = *(const f32x4*)(xrow + 3 * 32 + koff);
    f32x4 xp7 = *(const f32x4*)(xrow + 3 * 32 + koff + 4);
    asm volatile("" : "+v"(xp0), "+v"(xp1), "+v"(xp2), "+v"(xp3),
                      "+v"(xp4), "+v"(xp5), "+v"(xp6), "+v"(xp7));

    const unsigned int sentinel = (unsigned)nN << 7;   // src*128 prescale
    if (t < 64) bcnt[t] = 0;
#pragma unroll
    for (int k = 0; k < 7; k++) el[k * 256 + t] = sentinel;
    __syncthreads();

    // ---- load raw payloads + bin-rank via LDS atomics
    unsigned int pk[7]; int rk[7];
#pragma unroll
    for (int k = 0; k < 7; k++) {
        int idx = k * 256 + t;
        if (idx < n) {
            unsigned int p = csr_packed[e0 + idx];
            pk[k] = p;
            rk[k] = atomicAdd(&bcnt[(p >> 17) & 63], 1);
        } else pk[k] = 0xFFFFFFFFu;
    }
    __syncthreads();

    // ---- wave 0: padded-length scan + degree-bitonic slot assignment
    if (wave == 0) {
        int dg = bcnt[lane];
        int pl = (dg + 7) & ~7;
        int s = pl;
#pragma unroll
        for (int off = 1; off < 64; off <<= 1) {
            int u = __shfl_up(s, off);
            if (lane >= off) s += u;
        }
        bpst[lane] = s - pl;
        unsigned key = ((unsigned)dg << 6) | (unsigned)lane;
#pragma unroll
        for (int k = 2; k <= 64; k <<= 1) {
#pragma unroll
            for (int j = k >> 1; j > 0; j >>= 1) {
                unsigned other = __shfl_xor(key, j);
                bool lower = (lane & j) == 0;
                bool asc   = (lane & k) == 0;
                unsigned mn = min(key, other), mx = max(key, other);
                key = (lower == asc) ? mn : mx;
            }
        }
        int rowid = key & 63;
        bst[lane] = bpst[rowid];
        bdg[lane] = (int)(key >> 6);
        brw[lane] = rowid;
    }
    __syncthreads();

    // ---- scatter sorted (pre-scaled src*128) into el
#pragma unroll
    for (int k = 0; k < 7; k++) {
        if (pk[k] != 0xFFFFFFFFu) {
            int dl = (pk[k] >> 17) & 63;
            el[bpst[dl] + rk[k]] = (pk[k] & 0x1FFFFu) << 7;
        }
    }
    __syncthreads();

    // ---- gather: 8 row-groups/wave, 8 lanes x 16B = one 128B line per edge
    {
        const int g = lane >> 3;   // row group 0..7
        const int c = lane & 7;    // 16B sub-segment of the 128B row
        const unsigned char* plane = xq + c * 16;
#pragma unroll
        for (int set = 0; set < 2; set++) {
            const int r  = wave * 16 + set * 8 + g;
            const int st = bst[r];
            const int dg = bdg[r];
            const int pl = (dg + 7) & ~7;
            const unsigned int* ep = el + st;

            f32x2 a0{0.f,0.f}, a1{0.f,0.f}, a2{0.f,0.f}, a3{0.f,0.f},
                  a4{0.f,0.f}, a5{0.f,0.f}, a6{0.f,0.f}, a7{0.f,0.f};
            for (int j = 0; j < pl; j += 8) {
                const unsigned int s0 = ep[j + ((0 + g) & 7)];
                const unsigned int s1 = ep[j + ((1 + g) & 7)];
                const unsigned int s2 = ep[j + ((2 + g) & 7)];
                const unsigned int s3 = ep[j + ((3 + g) & 7)];
                const unsigned int s4 = ep[j + ((4 + g) & 7)];
                const unsigned int s5 = ep[j + ((5 + g) & 7)];
                const unsigned int s6 = ep[j + ((6 + g) & 7)];
                const unsigned int s7 = ep[j + ((7 + g) & 7)];
                const uint4 v0 = *(const uint4*)(plane + s0);
                const uint4 v1 = *(const uint4*)(plane + s1);
                const uint4 v2 = *(const uint4*)(plane + s2);
                const uint4 v3 = *(const uint4*)(plane + s3);
                const uint4 v4 = *(const uint4*)(plane + s4);
                const uint4 v5 = *(const uint4*)(plane + s5);
                const uint4 v6 = *(const uint4*)(plane + s6);
                const uint4 v7 = *(const uint4*)(plane + s7);
                f32x2 p;
                p = __builtin_amdgcn_cvt_pk_f32_fp8(v0.x, false); a0 += p;
                p = __builtin_amdgcn_cvt_pk_f32_fp8(v0.x, true);  a1 += p;
                p = __builtin_amdgcn_cvt_pk_f32_fp8(v0.y, false); a2 += p;
                p = __builtin_amdgcn_cvt_pk_f32_fp8(v0.y, true);  a3 += p;
                p = __builtin_amdgcn_cvt_pk_f32_fp8(v0.z, false); a4 += p;
                p = __builtin_amdgcn_cvt_pk_f32_fp8(v0.z, true);  a5 += p;
                p = __builtin_amdgcn_cvt_pk_f32_fp8(v0.w, false); a6 += p;
                p = __builtin_amdgcn_cvt_pk_f32_fp8(v0.w, true);  a7 += p;
                p = __builtin_amdgcn_cvt_pk_f32_fp8(v1.x, false); a0 += p;
                p = __builtin_amdgcn_cvt_pk_f32_fp8(v1.x, true);  a1 += p;
                p = __builtin_amdgcn_cvt_pk_f32_fp8(v1.y, false); a2 += p;
                p = __builtin_amdgcn_cvt_pk_f32_fp8(v1.y, true);  a3 += p;
                p = __builtin_amdgcn_cvt_pk_f32_fp8(v1.z, false); a4 += p;
                p = __builtin_amdgcn_cvt_pk_f32_fp8(v1.z, true);  a5 += p;
                p = __builtin_amdgcn_cvt_pk_f32_fp8(v1.w, false); a6 += p;
                p = __builtin_amdgcn_cvt_pk_f32_fp8(v1.w, true);  a7 += p;
                p = __builtin_amdgcn_cvt_pk_f32_fp8(v2.x, false); a0 += p;
                p = __builtin_amdgcn_cvt_pk_f32_fp8(v2.x, true);  a1 += p;
                p = __builtin_amdgcn_cvt_pk_f32_fp8(v2.y, false); a2 += p;
                p = __builtin_amdgcn_cvt_pk_f32_fp8(v2.y, true);  a3 += p;
                p = __builtin_amdgcn_cvt_pk_f32_fp8(v2.z, false); a4 += p;
                p = __builtin_amdgcn_cvt_pk_f32_fp8(v2.z, true);  a5 += p;
                p = __builtin_amdgcn_cvt_pk_f32_fp8(v2.w, false); a6 += p;
                p = __builtin_amdgcn_cvt_pk_f32_fp8(v2.w, true);  a7 += p;
                p = __builtin_amdgcn_cvt_pk_f32_fp8(v3.x, false); a0 += p;
                p = __builtin_amdgcn_cvt_pk_f32_fp8(v3.x, true);  a1 += p;
                p = __builtin_amdgcn_cvt_pk_f32_fp8(v3.y, false); a2 += p;
                p = __builtin_amdgcn_cvt_pk_f32_fp8(v3.y, true);  a3 += p;
                p = __builtin_amdgcn_cvt_pk_f32_fp8(v3.z, false); a4 += p;
                p = __builtin_amdgcn_cvt_pk_f32_fp8(v3.z, true);  a5 += p;
                p = __builtin_amdgcn_cvt_pk_f32_fp8(v3.w, false); a6 += p;
                p = __builtin_amdgcn_cvt_pk_f32_fp8(v3.w, true);  a7 += p;
                p = __builtin_amdgcn_cvt_pk_f32_fp8(v4.x, false); a0 += p;
                p = __builtin_amdgcn_cvt_pk_f32_fp8(v4.x, true);  a1 += p;
                p = __builtin_amdgcn_cvt_pk_f32_fp8(v4.y, false); a2 += p;
                p = __builtin_amdgcn_cvt_pk_f32_fp8(v4.y, true);  a3 += p;
                p = __builtin_amdgcn_cvt_pk_f32_fp8(v4.z, false); a4 += p;
                p = __builtin_amdgcn_cvt_pk_f32_fp8(v4.z, true);  a5 += p;
                p = __builtin_amdgcn_cvt_pk_f32_fp8(v4.w, false); a6 += p;
                p = __builtin_amdgcn_cvt_pk_f32_fp8(v4.w, true);  a7 += p;
                p = __builtin_amdgcn_cvt_pk_f32_fp8(v5.x, false); a0 += p;
                p = __builtin_amdgcn_cvt_pk_f32_fp8(v5.x, true);  a1 += p;
                p = __builtin_amdgcn_cvt_pk_f32_fp8(v5.y, false); a2 += p;
                p = __builtin_amdgcn_cvt_pk_f32_fp8(v5.y, true);  a3 += p;
                p = __builtin_amdgcn_cvt_pk_f32_fp8(v5.z, false); a4 += p;
                p = __builtin_amdgcn_cvt_pk_f32_fp8(v5.z, true);  a5 += p;
                p = __builtin_amdgcn_cvt_pk_f32_fp8(v5.w, false); a6 += p;
                p = __builtin_amdgcn_cvt_pk_f32_fp8(v5.w, true);  a7 += p;
                p = __builtin_amdgcn_cvt_pk_f32_fp8(v6.x, false); a0 += p;
                p = __builtin_amdgcn_cvt_pk_f32_fp8(v6.x, true);  a1 += p;
                p = __builtin_amdgcn_cvt_pk_f32_fp8(v6.y, false); a2 += p;
                p = __builtin_amdgcn_cvt_pk_f32_fp8(v6.y, true);  a3 += p;
                p = __builtin_amdgcn_cvt_pk_f32_fp8(v6.z, false); a4 += p;
                p = __builtin_amdgcn_cvt_pk_f32_fp8(v6.z, true);  a5 += p;
                p = __builtin_amdgcn_cvt_pk_f32_fp8(v6.w, false); a6 += p;
                p = __builtin_amdgcn_cvt_pk_f32_fp8(v6.w, true);  a7 += p;
                p = __builtin_amdgcn_cvt_pk_f32_fp8(v7.x, false); a0 += p;
                p = __builtin_amdgcn_cvt_pk_f32_fp8(v7.x, true);  a1 += p;
                p = __builtin_amdgcn_cvt_pk_f32_fp8(v7.y, false); a2 += p;
                p = __builtin_amdgcn_cvt_pk_f32_fp8(v7.y, true);  a3 += p;
                p = __builtin_amdgcn_cvt_pk_f32_fp8(v7.z, false); a4 += p;
                p = __builtin_amdgcn_cvt_pk_f32_fp8(v7.z, true);  a5 += p;
                p = __builtin_amdgcn_cvt_pk_f32_fp8(v7.w, false); a6 += p;
                p = __builtin_amdgcn_cvt_pk_f32_fp8(v7.w, true);  a7 += p;
            }
            const float rd = 1.0f / (float)((dg > 0) ? dg : 1);
            a0 *= rd; a1 *= rd; a2 *= rd; a3 *= rd;
            a4 *= rd; a5 *= rd; a6 *= rd; a7 *= rd;
            unsigned int w0, w1, w2, w3, w4, w5, w6, w7;
            asm("v_cvt_pk_bf16_f32 %0, %1, %2" : "=v"(w0) : "v"(a0.x), "v"(a0.y));
            asm("v_cvt_pk_bf16_f32 %0, %1, %2" : "=v"(w1) : "v"(a1.x), "v"(a1.y));
            asm("v_cvt_pk_bf16_f32 %0, %1, %2" : "=v"(w2) : "v"(a2.x), "v"(a2.y));
            asm("v_cvt_pk_bf16_f32 %0, %1, %2" : "=v"(w3) : "v"(a3.x), "v"(a3.y));
            asm("v_cvt_pk_bf16_f32 %0, %1, %2" : "=v"(w4) : "v"(a4.x), "v"(a4.y));
            asm("v_cvt_pk_bf16_f32 %0, %1, %2" : "=v"(w5) : "v"(a5.x), "v"(a5.y));
            asm("v_cvt_pk_bf16_f32 %0, %1, %2" : "=v"(w6) : "v"(a6.x), "v"(a6.y));
            asm("v_cvt_pk_bf16_f32 %0, %1, %2" : "=v"(w7) : "v"(a7.x), "v"(a7.y));
            short* np = &Ntile[brw[r] * 136 + c * 16];
            u32x4 olo = {w0, w1, w2, w3};
            u32x4 ohi = {w4, w5, w6, w7};
            *(u32x4*)np = olo;
            *(u32x4*)(np + 8) = ohi;
        }
    }
    __syncthreads();

    // ---- GEMM: x-half from prefetched registers, neigh-half from Ntile
    f32x4 acc[8];
#pragma unroll
    for (int c = 0; c < 8; c++) acc[c] = f32x4{0.f, 0.f, 0.f, 0.f};

#pragma unroll
    for (int f = 0; f < 8; f++) {
        bf16x8 af;
        if (f < 4) {
            f32x4 v0, v1;
            if (f == 0)      { v0 = xp0; v1 = xp1; }
            else if (f == 1) { v0 = xp2; v1 = xp3; }
            else if (f == 2) { v0 = xp4; v1 = xp5; }
            else             { v0 = xp6; v1 = xp7; }
            unsigned int r0, r1, r2, r3;
            asm("v_cvt_pk_bf16_f32 %0, %1, %2" : "=v"(r0) : "v"(v0.x), "v"(v0.y));
            asm("v_cvt_pk_bf16_f32 %0, %1, %2" : "=v"(r1) : "v"(v0.z), "v"(v0.w));
            asm("v_cvt_pk_bf16_f32 %0, %1, %2" : "=v"(r2) : "v"(v1.x), "v"(v1.y));
            asm("v_cvt_pk_bf16_f32 %0, %1, %2" : "=v"(r3) : "v"(v1.z), "v"(v1.w));
            union { unsigned int u[4]; bf16x8 v; } cv;
            cv.u[0] = r0; cv.u[1] = r1; cv.u[2] = r2; cv.u[3] = r3;
            af = cv.v;
        } else {
            af = *(const bf16x8*)&Ntile[arow * 136 + (f - 4) * 32 + koff];
        }
#pragma unroll
        for (int c = 0; c < 8; c++) {
            bf16x8 bf = *(const bf16x8*)(WF + ((size_t)(f * 8 + c) * 64 + lane) * 8);
            acc[c] = __builtin_amdgcn_mfma_f32_16x16x32_bf16(af, bf, acc[c], 0, 0, 0);
        }
    }

    // ---- epilogue: C/D layout col=lane&15, row=(lane>>4)*4+reg  [m89]
    const int orow0 = bucket * 64 + wave * 16 + (lane >> 4) * 4;
    const int ocol  = lane & 15;
#pragma unroll
    for (int c = 0; c < 8; c++) {
        const float bv = bias[c * 16 + ocol];
#pragma unroll
        for (int r = 0; r < 4; r++) {
            int row = orow0 + r;
            if (row < nN)
                out[(size_t)row * OUT_DIM + c * 16 + ocol] = acc[c][r] + bv;
        }
    }
}

// ---------------------------------------------------------------------------
extern "C" void kernel_launch(void* const* d_in, const int* in_sizes, int n_in,
                              void* d_out, int out_size, void* d_ws, size_t ws_size,
                              hipStream_t stream) {
    const float* x        = (const float*)d_in[0];
    const int*   edge_src = (const int*)d_in[1];
    const int*   edge_dst = (const int*)d_in[2];
    const float* W        = (const float*)d_in[3];
    const float* bias     = (const float*)d_in[4];
    float* out = (float*)d_out;

    const int nN = in_sizes[0] / IN_DIM;   // 100000
    const int nE = in_sizes[1];            // 1600000
    const int nb = (nN + 63) >> 6;         // 1563 buckets

    // ws (~24.1 MB): cursor[2048], csr_packed[nb*PADCAP] u32 (11.2MB),
    //   xq full plane [(nN+1)][128] fp8 (12.8MB), WF bf16 (64KB)
    int* cursor = (int*)d_ws;
    unsigned int* csr_packed = (unsigned int*)(cursor + 2048);
    unsigned char* xq = (unsigned char*)(csr_packed + (size_t)nb * PADCAP);
    unsigned short* WF = (unsigned short*)(xq + (size_t)(nN + 1) * 128);

    const int total8 = nN * IN_DIM / 8;              // 1.6M
    const int nconv  = (total8 + 255) / 256;         // 6250
    const int ninit  = (nb + 255) / 256;             // 7
    prep_kernel<<<nconv + 17 + ninit, 256, 0, stream>>>(x, xq, W, WF, cursor,
                                                        nN, total8, nconv, nb);

    const int eblk = (nE + EPB - 1) / EPB;           // 196
    place_kernel<<<eblk, 1024, 0, stream>>>(edge_src, edge_dst, cursor, csr_packed, nE, nb);

    fused_kernel<<<nb, 256, 0, stream>>>(xq, csr_packed, cursor, WF, x, bias, out, nN);
}

// Round 26
// 94.815 us; speedup vs baseline: 1.1669x; 1.1669x over previous
//
#include <hip/hip_runtime.h>

#define IN_DIM 128
#define OUT_DIM 128
#define PADCAP 1792   // per-bucket capacity: max count ~1184 + 64*7 pad = 1632 < 1792
#define EPB 8192      // edges per place block (196 blocks)

typedef short bf16x8 __attribute__((ext_vector_type(8)));
typedef float f32x4 __attribute__((ext_vector_type(4)));
typedef float f32x2 __attribute__((ext_vector_type(2)));
typedef unsigned int u32x4 __attribute__((ext_vector_type(4)));

__device__ __forceinline__ unsigned short f2bf(float f) {
    union { float f; unsigned int u; } v; v.f = f;
    unsigned int u = v.u;
    u += 0x7FFFu + ((u >> 16) & 1u);   // round-to-nearest-even
    return (unsigned short)(u >> 16);
}

// ---------------------------------------------------------------------------
// prep: fused convertq (x -> fp8, ONE full-row plane [(nN+1)][128]) +
// convertW (MFMA fragment layout) + cursor init + sentinel row.
// ---------------------------------------------------------------------------
__global__ __launch_bounds__(256) void prep_kernel(const float* __restrict__ x,
                                                   unsigned char* __restrict__ xq,
                                                   const float* __restrict__ W,
                                                   unsigned short* __restrict__ WF,
                                                   int* __restrict__ cursor,
                                                   int nN, int total8, int nconv, int nb) {
    const int b = blockIdx.x;
    const int t = threadIdx.x;
    if (b < nconv) {
        int i = b * 256 + t;
        if (i >= total8) return;
        const float4* p = (const float4*)x + (size_t)i * 2;
        float4 v0 = p[0], v1 = p[1];
        int w0 = 0, w1 = 0;
        w0 = __builtin_amdgcn_cvt_pk_fp8_f32(v0.x, v0.y, w0, false);
        w0 = __builtin_amdgcn_cvt_pk_fp8_f32(v0.z, v0.w, w0, true);
        w1 = __builtin_amdgcn_cvt_pk_fp8_f32(v1.x, v1.y, w1, false);
        w1 = __builtin_amdgcn_cvt_pk_fp8_f32(v1.z, v1.w, w1, true);
        uint2 o; o.x = (unsigned int)w0; o.y = (unsigned int)w1;
        *(uint2*)(xq + (size_t)i * 8) = o;   // row-major [(nN+1)][128]
    } else if (b < nconv + 16) {
        int tt = (b - nconv) * 256 + t;   // 0..4095
        int frag = tt >> 6, lane = tt & 63;
        int f = frag >> 3, c = frag & 7;
        int col = c * 16 + (lane & 15);
        int kbase = f * 32 + (lane >> 4) * 8;
        bf16x8 h;
#pragma unroll
        for (int i = 0; i < 8; i++)
            h[i] = (short)f2bf(W[(size_t)(kbase + i) * OUT_DIM + col]);
        *(bf16x8*)(WF + (size_t)tt * 8) = h;
    } else if (b == nconv + 16) {
        if (t < 32)
            *(unsigned int*)(xq + (size_t)nN * 128 + t * 4) = 0u;   // sentinel row
    } else {
        int i = (b - nconv - 17) * 256 + t;
        if (i < nb) cursor[i] = i * PADCAP;
    }
}

// ---------------------------------------------------------------------------
// place: edges -> per-bucket segments. payload = (dstlocal<<17)|src.
// ---------------------------------------------------------------------------
__global__ __launch_bounds__(1024) void place_kernel(const int* __restrict__ src,
                                                     const int* __restrict__ dst,
                                                     int* __restrict__ cursor,
                                                     unsigned int* __restrict__ csr_packed,
                                                     int nE, int nb) {
    __shared__ int lcnt[2048];
    __shared__ int lbase[2048];
    const int t = threadIdx.x;
    for (int i = t; i < nb; i += 1024) lcnt[i] = 0;
    __syncthreads();
    const int e0 = blockIdx.x * EPB;
    unsigned int meta[EPB / 1024];
#pragma unroll
    for (int k = 0; k < EPB / 1024; k++) {
        int e = e0 + k * 1024 + t;
        if (e < nE) {
            int d = dst[e];
            int bk = d >> 6, dl = d & 63;
            int r = atomicAdd(&lcnt[bk], 1);
            meta[k] = ((unsigned)bk << 20) | ((unsigned)dl << 14) | (unsigned)r;
        } else meta[k] = 0xFFFFFFFFu;
    }
    __syncthreads();
    for (int i = t; i < nb; i += 1024) {
        int c = lcnt[i];
        lbase[i] = c ? atomicAdd(&cursor[i], c) : 0;   // absolute base
    }
    __syncthreads();
#pragma unroll
    for (int k = 0; k < EPB / 1024; k++) {
        if (meta[k] != 0xFFFFFFFFu) {
            int e = e0 + k * 1024 + t;
            unsigned int m = meta[k];
            int bk = m >> 20, dl = (m >> 14) & 63, r = m & 0x3FFF;
            csr_packed[lbase[bk] + r] = ((unsigned)dl << 17) | (unsigned)src[e];
        }
    }
}

// ---------------------------------------------------------------------------
// fused: ONE block per bucket. sort -> full-row fp8 gather -> Ntile (LDS) ->
// barrier -> zero-barrier MFMA GEMM (r24-proven form; x from global after the
// barrier). ONLY change vs r24: __launch_bounds__(256, 6) — LDS 26.1KB x 6 =
// 153KB fits, VGPR 40 <= 85; tests the occupancy lever in isolation.
// ---------------------------------------------------------------------------
__global__ __launch_bounds__(256, 6) void fused_kernel(const unsigned char* __restrict__ xq,
                                                       const unsigned int* __restrict__ csr_packed,
                                                       const int* __restrict__ cursor,
                                                       const unsigned short* __restrict__ WF,
                                                       const float* __restrict__ x,
                                                       const float* __restrict__ bias,
                                                       float* __restrict__ out, int nN) {
    __shared__ unsigned int el[PADCAP];
    __shared__ __align__(16) short Ntile[64 * 136];
    __shared__ int bcnt[64];
    __shared__ int bpst[64];
    __shared__ int bst[64];
    __shared__ int bdg[64];
    __shared__ int brw[64];

    const int bucket = blockIdx.x;
    const int t = threadIdx.x;
    const int lane = t & 63;
    const int wave = t >> 6;

    const size_t e0 = (size_t)bucket * PADCAP;
    int n = cursor[bucket] - bucket * PADCAP;
    if (n > PADCAP) n = PADCAP;

    const unsigned int sentinel = (unsigned)nN << 7;   // src*128 prescale
    if (t < 64) bcnt[t] = 0;
#pragma unroll
    for (int k = 0; k < 7; k++) el[k * 256 + t] = sentinel;
    __syncthreads();

    // ---- load raw payloads + bin-rank via LDS atomics
    unsigned int pk[7]; int rk[7];
#pragma unroll
    for (int k = 0; k < 7; k++) {
        int idx = k * 256 + t;
        if (idx < n) {
            unsigned int p = csr_packed[e0 + idx];
            pk[k] = p;
            rk[k] = atomicAdd(&bcnt[(p >> 17) & 63], 1);
        } else pk[k] = 0xFFFFFFFFu;
    }
    __syncthreads();

    // ---- wave 0: padded-length scan + degree-bitonic slot assignment
    if (wave == 0) {
        int dg = bcnt[lane];
        int pl = (dg + 7) & ~7;
        int s = pl;
#pragma unroll
        for (int off = 1; off < 64; off <<= 1) {
            int u = __shfl_up(s, off);
            if (lane >= off) s += u;
        }
        bpst[lane] = s - pl;
        unsigned key = ((unsigned)dg << 6) | (unsigned)lane;
#pragma unroll
        for (int k = 2; k <= 64; k <<= 1) {
#pragma unroll
            for (int j = k >> 1; j > 0; j >>= 1) {
                unsigned other = __shfl_xor(key, j);
                bool lower = (lane & j) == 0;
                bool asc   = (lane & k) == 0;
                unsigned mn = min(key, other), mx = max(key, other);
                key = (lower == asc) ? mn : mx;
            }
        }
        int rowid = key & 63;
        bst[lane] = bpst[rowid];
        bdg[lane] = (int)(key >> 6);
        brw[lane] = rowid;
    }
    __syncthreads();

    // ---- scatter sorted (pre-scaled src*128) into el
#pragma unroll
    for (int k = 0; k < 7; k++) {
        if (pk[k] != 0xFFFFFFFFu) {
            int dl = (pk[k] >> 17) & 63;
            el[bpst[dl] + rk[k]] = (pk[k] & 0x1FFFFu) << 7;
        }
    }
    __syncthreads();

    // ---- gather: 8 row-groups/wave, 8 lanes x 16B = one 128B line per edge
    {
        const int g = lane >> 3;   // row group 0..7
        const int c = lane & 7;    // 16B sub-segment of the 128B row
        const unsigned char* plane = xq + c * 16;
#pragma unroll
        for (int set = 0; set < 2; set++) {
            const int r  = wave * 16 + set * 8 + g;
            const int st = bst[r];
            const int dg = bdg[r];
            const int pl = (dg + 7) & ~7;
            const unsigned int* ep = el + st;

            f32x2 a0{0.f,0.f}, a1{0.f,0.f}, a2{0.f,0.f}, a3{0.f,0.f},
                  a4{0.f,0.f}, a5{0.f,0.f}, a6{0.f,0.f}, a7{0.f,0.f};
            for (int j = 0; j < pl; j += 8) {
                const unsigned int s0 = ep[j + ((0 + g) & 7)];
                const unsigned int s1 = ep[j + ((1 + g) & 7)];
                const unsigned int s2 = ep[j + ((2 + g) & 7)];
                const unsigned int s3 = ep[j + ((3 + g) & 7)];
                const unsigned int s4 = ep[j + ((4 + g) & 7)];
                const unsigned int s5 = ep[j + ((5 + g) & 7)];
                const unsigned int s6 = ep[j + ((6 + g) & 7)];
                const unsigned int s7 = ep[j + ((7 + g) & 7)];
                const uint4 v0 = *(const uint4*)(plane + s0);
                const uint4 v1 = *(const uint4*)(plane + s1);
                const uint4 v2 = *(const uint4*)(plane + s2);
                const uint4 v3 = *(const uint4*)(plane + s3);
                const uint4 v4 = *(const uint4*)(plane + s4);
                const uint4 v5 = *(const uint4*)(plane + s5);
                const uint4 v6 = *(const uint4*)(plane + s6);
                const uint4 v7 = *(const uint4*)(plane + s7);
                f32x2 p;
                p = __builtin_amdgcn_cvt_pk_f32_fp8(v0.x, false); a0 += p;
                p = __builtin_amdgcn_cvt_pk_f32_fp8(v0.x, true);  a1 += p;
                p = __builtin_amdgcn_cvt_pk_f32_fp8(v0.y, false); a2 += p;
                p = __builtin_amdgcn_cvt_pk_f32_fp8(v0.y, true);  a3 += p;
                p = __builtin_amdgcn_cvt_pk_f32_fp8(v0.z, false); a4 += p;
                p = __builtin_amdgcn_cvt_pk_f32_fp8(v0.z, true);  a5 += p;
                p = __builtin_amdgcn_cvt_pk_f32_fp8(v0.w, false); a6 += p;
                p = __builtin_amdgcn_cvt_pk_f32_fp8(v0.w, true);  a7 += p;
                p = __builtin_amdgcn_cvt_pk_f32_fp8(v1.x, false); a0 += p;
                p = __builtin_amdgcn_cvt_pk_f32_fp8(v1.x, true);  a1 += p;
                p = __builtin_amdgcn_cvt_pk_f32_fp8(v1.y, false); a2 += p;
                p = __builtin_amdgcn_cvt_pk_f32_fp8(v1.y, true);  a3 += p;
                p = __builtin_amdgcn_cvt_pk_f32_fp8(v1.z, false); a4 += p;
                p = __builtin_amdgcn_cvt_pk_f32_fp8(v1.z, true);  a5 += p;
                p = __builtin_amdgcn_cvt_pk_f32_fp8(v1.w, false); a6 += p;
                p = __builtin_amdgcn_cvt_pk_f32_fp8(v1.w, true);  a7 += p;
                p = __builtin_amdgcn_cvt_pk_f32_fp8(v2.x, false); a0 += p;
                p = __builtin_amdgcn_cvt_pk_f32_fp8(v2.x, true);  a1 += p;
                p = __builtin_amdgcn_cvt_pk_f32_fp8(v2.y, false); a2 += p;
                p = __builtin_amdgcn_cvt_pk_f32_fp8(v2.y, true);  a3 += p;
                p = __builtin_amdgcn_cvt_pk_f32_fp8(v2.z, false); a4 += p;
                p = __builtin_amdgcn_cvt_pk_f32_fp8(v2.z, true);  a5 += p;
                p = __builtin_amdgcn_cvt_pk_f32_fp8(v2.w, false); a6 += p;
                p = __builtin_amdgcn_cvt_pk_f32_fp8(v2.w, true);  a7 += p;
                p = __builtin_amdgcn_cvt_pk_f32_fp8(v3.x, false); a0 += p;
                p = __builtin_amdgcn_cvt_pk_f32_fp8(v3.x, true);  a1 += p;
                p = __builtin_amdgcn_cvt_pk_f32_fp8(v3.y, false); a2 += p;
                p = __builtin_amdgcn_cvt_pk_f32_fp8(v3.y, true);  a3 += p;
                p = __builtin_amdgcn_cvt_pk_f32_fp8(v3.z, false); a4 += p;
                p = __builtin_amdgcn_cvt_pk_f32_fp8(v3.z, true);  a5 += p;
                p = __builtin_amdgcn_cvt_pk_f32_fp8(v3.w, false); a6 += p;
                p = __builtin_amdgcn_cvt_pk_f32_fp8(v3.w, true);  a7 += p;
                p = __builtin_amdgcn_cvt_pk_f32_fp8(v4.x, false); a0 += p;
                p = __builtin_amdgcn_cvt_pk_f32_fp8(v4.x, true);  a1 += p;
                p = __builtin_amdgcn_cvt_pk_f32_fp8(v4.y, false); a2 += p;
                p = __builtin_amdgcn_cvt_pk_f32_fp8(v4.y, true);  a3 += p;
                p = __builtin_amdgcn_cvt_pk_f32_fp8(v4.z, false); a4 += p;
                p = __builtin_amdgcn_cvt_pk_f32_fp8(v4.z, true);  a5 += p;
                p = __builtin_amdgcn_cvt_pk_f32_fp8(v4.w, false); a6 += p;
                p = __builtin_amdgcn_cvt_pk_f32_fp8(v4.w, true);  a7 += p;
                p = __builtin_amdgcn_cvt_pk_f32_fp8(v5.x, false); a0 += p;
                p = __builtin_amdgcn_cvt_pk_f32_fp8(v5.x, true);  a1 += p;
                p = __builtin_amdgcn_cvt_pk_f32_fp8(v5.y, false); a2 += p;
                p = __builtin_amdgcn_cvt_pk_f32_fp8(v5.y, true);  a3 += p;
                p = __builtin_amdgcn_cvt_pk_f32_fp8(v5.z, false); a4 += p;
                p = __builtin_amdgcn_cvt_pk_f32_fp8(v5.z, true);  a5 += p;
                p = __builtin_amdgcn_cvt_pk_f32_fp8(v5.w, false); a6 += p;
                p = __builtin_amdgcn_cvt_pk_f32_fp8(v5.w, true);  a7 += p;
                p = __builtin_amdgcn_cvt_pk_f32_fp8(v6.x, false); a0 += p;
                p = __builtin_amdgcn_cvt_pk_f32_fp8(v6.x, true);  a1 += p;
                p = __builtin_amdgcn_cvt_pk_f32_fp8(v6.y, false); a2 += p;
                p = __builtin_amdgcn_cvt_pk_f32_fp8(v6.y, true);  a3 += p;
                p = __builtin_amdgcn_cvt_pk_f32_fp8(v6.z, false); a4 += p;
                p = __builtin_amdgcn_cvt_pk_f32_fp8(v6.z, true);  a5 += p;
                p = __builtin_amdgcn_cvt_pk_f32_fp8(v6.w, false); a6 += p;
                p = __builtin_amdgcn_cvt_pk_f32_fp8(v6.w, true);  a7 += p;
                p = __builtin_amdgcn_cvt_pk_f32_fp8(v7.x, false); a0 += p;
                p = __builtin_amdgcn_cvt_pk_f32_fp8(v7.x, true);  a1 += p;
                p = __builtin_amdgcn_cvt_pk_f32_fp8(v7.y, false); a2 += p;
                p = __builtin_amdgcn_cvt_pk_f32_fp8(v7.y, true);  a3 += p;
                p = __builtin_amdgcn_cvt_pk_f32_fp8(v7.z, false); a4 += p;
                p = __builtin_amdgcn_cvt_pk_f32_fp8(v7.z, true);  a5 += p;
                p = __builtin_amdgcn_cvt_pk_f32_fp8(v7.w, false); a6 += p;
                p = __builtin_amdgcn_cvt_pk_f32_fp8(v7.w, true);  a7 += p;
            }
            const float rd = 1.0f / (float)((dg > 0) ? dg : 1);
            a0 *= rd; a1 *= rd; a2 *= rd; a3 *= rd;
            a4 *= rd; a5 *= rd; a6 *= rd; a7 *= rd;
            unsigned int w0, w1, w2, w3, w4, w5, w6, w7;
            asm("v_cvt_pk_bf16_f32 %0, %1, %2" : "=v"(w0) : "v"(a0.x), "v"(a0.y));
            asm("v_cvt_pk_bf16_f32 %0, %1, %2" : "=v"(w1) : "v"(a1.x), "v"(a1.y));
            asm("v_cvt_pk_bf16_f32 %0, %1, %2" : "=v"(w2) : "v"(a2.x), "v"(a2.y));
            asm("v_cvt_pk_bf16_f32 %0, %1, %2" : "=v"(w3) : "v"(a3.x), "v"(a3.y));
            asm("v_cvt_pk_bf16_f32 %0, %1, %2" : "=v"(w4) : "v"(a4.x), "v"(a4.y));
            asm("v_cvt_pk_bf16_f32 %0, %1, %2" : "=v"(w5) : "v"(a5.x), "v"(a5.y));
            asm("v_cvt_pk_bf16_f32 %0, %1, %2" : "=v"(w6) : "v"(a6.x), "v"(a6.y));
            asm("v_cvt_pk_bf16_f32 %0, %1, %2" : "=v"(w7) : "v"(a7.x), "v"(a7.y));
            short* np = &Ntile[brw[r] * 136 + c * 16];
            u32x4 olo = {w0, w1, w2, w3};
            u32x4 ohi = {w4, w5, w6, w7};
            *(u32x4*)np = olo;
            *(u32x4*)(np + 8) = ohi;
        }
    }
    __syncthreads();

    // ---- GEMM: x-half from global f32, neigh-half from Ntile, B from WF
    f32x4 acc[8];
#pragma unroll
    for (int c = 0; c < 8; c++) acc[c] = f32x4{0.f, 0.f, 0.f, 0.f};

    const int arow = wave * 16 + (lane & 15);
    const int koff = (lane >> 4) * 8;
    const int rowc = min(bucket * 64 + arow, nN - 1);
    const float* xrow = x + (size_t)rowc * IN_DIM;

#pragma unroll
    for (int f = 0; f < 8; f++) {
        bf16x8 af;
        if (f < 4) {
            const float* px = xrow + f * 32 + koff;
            float4 v0 = *(const float4*)px;
            float4 v1 = *(const float4*)(px + 4);
            unsigned int r0, r1, r2, r3;
            asm("v_cvt_pk_bf16_f32 %0, %1, %2" : "=v"(r0) : "v"(v0.x), "v"(v0.y));
            asm("v_cvt_pk_bf16_f32 %0, %1, %2" : "=v"(r1) : "v"(v0.z), "v"(v0.w));
            asm("v_cvt_pk_bf16_f32 %0, %1, %2" : "=v"(r2) : "v"(v1.x), "v"(v1.y));
            asm("v_cvt_pk_bf16_f32 %0, %1, %2" : "=v"(r3) : "v"(v1.z), "v"(v1.w));
            union { unsigned int u[4]; bf16x8 v; } cv;
            cv.u[0] = r0; cv.u[1] = r1; cv.u[2] = r2; cv.u[3] = r3;
            af = cv.v;
        } else {
            af = *(const bf16x8*)&Ntile[arow * 136 + (f - 4) * 32 + koff];
        }
#pragma unroll
        for (int c = 0; c < 8; c++) {
            bf16x8 bf = *(const bf16x8*)(WF + ((size_t)(f * 8 + c) * 64 + lane) * 8);
            acc[c] = __builtin_amdgcn_mfma_f32_16x16x32_bf16(af, bf, acc[c], 0, 0, 0);
        }
    }

    // ---- epilogue: C/D layout col=lane&15, row=(lane>>4)*4+reg  [m89]
    const int orow0 = bucket * 64 + wave * 16 + (lane >> 4) * 4;
    const int ocol  = lane & 15;
#pragma unroll
    for (int c = 0; c < 8; c++) {
        const float bv = bias[c * 16 + ocol];
#pragma unroll
        for (int r = 0; r < 4; r++) {
            int row = orow0 + r;
            if (row < nN)
                out[(size_t)row * OUT_DIM + c * 16 + ocol] = acc[c][r] + bv;
        }
    }
}

// ---------------------------------------------------------------------------
extern "C" void kernel_launch(void* const* d_in, const int* in_sizes, int n_in,
                              void* d_out, int out_size, void* d_ws, size_t ws_size,
                              hipStream_t stream) {
    const float* x        = (const float*)d_in[0];
    const int*   edge_src = (const int*)d_in[1];
    const int*   edge_dst = (const int*)d_in[2];
    const float* W        = (const float*)d_in[3];
    const float* bias     = (const float*)d_in[4];
    float* out = (float*)d_out;

    const int nN = in_sizes[0] / IN_DIM;   // 100000
    const int nE = in_sizes[1];            // 1600000
    const int nb = (nN + 63) >> 6;         // 1563 buckets

    // ws (~24.1 MB): cursor[2048], csr_packed[nb*PADCAP] u32 (11.2MB),
    //   xq full plane [(nN+1)][128] fp8 (12.8MB), WF bf16 (64KB)
    int* cursor = (int*)d_ws;
    unsigned int* csr_packed = (unsigned int*)(cursor + 2048);
    unsigned char* xq = (unsigned char*)(csr_packed + (size_t)nb * PADCAP);
    unsigned short* WF = (unsigned short*)(xq + (size_t)(nN + 1) * 128);

    const int total8 = nN * IN_DIM / 8;              // 1.6M
    const int nconv  = (total8 + 255) / 256;         // 6250
    const int ninit  = (nb + 255) / 256;             // 7
    prep_kernel<<<nconv + 17 + ninit, 256, 0, stream>>>(x, xq, W, WF, cursor,
                                                        nN, total8, nconv, nb);

    const int eblk = (nE + EPB - 1) / EPB;           // 196
    place_kernel<<<eblk, 1024, 0, stream>>>(edge_src, edge_dst, cursor, csr_packed, nE, nb);

    fused_kernel<<<nb, 256, 0, stream>>>(xq, csr_packed, cursor, WF, x, bias, out, nN);
}